// Round 7
// baseline (20.153 us; speedup 1.0000x reference)
//
#include <hip/hip_runtime.h>

// ROI pooling (bilinear resize of each ROI to 7x7), matching the JAX reference.
// image: (1, 200, 200, 512) f32 NHWC; rois: (1, 300, 4) f32 (x,y,w,h); out: (1,300,7,7,512) f32.
//
// R7: test the latency-bound hypothesis. 128-thread blocks, FOUR cells per block
// (4 cells/thread, 16 loads issued back-to-back before any blend -> 2x MLP vs R6).
// Keeps R6's zero-weight corner collapse, XCD-chunked swizzle, nontemporal stores.

#define POOL   7
#define N_ROI  300
#define IMG_W  200
#define CH4    128           // 512 channels / 4 = float4 groups per pixel
#define NCELL  (N_ROI * POOL * POOL)   // 14700
#define CELLS_PER_BLK 4
#define NBLK   (NCELL / CELLS_PER_BLK) // 3675
#define NXCD   8

typedef float f4 __attribute__((ext_vector_type(4)));

struct Cell {
    int c00, c01, c10, c11;   // float4 base indices of the 4 corner pixels
    float w00, w01, w10, w11;
};

__device__ inline Cell decode_cell(const f4* __restrict__ rois4, int b) {
    const int q = b % POOL;
    const int t = b / POOL;
    const int p = t % POOL;
    const int r = t / POOL;

    const f4 rv = rois4[r];
    const int x = (int)rv.x;
    const int y = (int)rv.y;
    const int w = (int)rv.z;
    const int h = (int)rv.w;

    // Legacy resize arithmetic, replicated in f32 exactly as the reference.
    const float sy = (float)p * ((float)h / 7.0f);
    const int y0 = (int)floorf(sy);
    const float fy = sy - (float)y0;
    // fy==0 -> y1 weight is exactly 0: collapse to y0 (skip a useless fetch).
    const int y1 = (fy == 0.0f) ? y0 : min(y0 + 1, h - 1);

    const float sx = (float)q * ((float)w / 7.0f);
    const int x0 = (int)floorf(sx);
    const float fx = sx - (float)x0;
    const int x1 = (fx == 0.0f) ? x0 : min(x0 + 1, w - 1);

    const int row0 = (y + y0) * IMG_W;
    const int row1 = (y + y1) * IMG_W;

    Cell cl;
    cl.c00 = (row0 + x + x0) * CH4;
    cl.c01 = (row0 + x + x1) * CH4;
    cl.c10 = (row1 + x + x0) * CH4;
    cl.c11 = (row1 + x + x1) * CH4;
    cl.w00 = (1.0f - fy) * (1.0f - fx);
    cl.w01 = (1.0f - fy) * fx;
    cl.w10 = fy * (1.0f - fx);
    cl.w11 = fy * fx;
    return cl;
}

__global__ __launch_bounds__(CH4) void roi_pool_kernel(
        const float* __restrict__ image,
        const float* __restrict__ rois,
        float* __restrict__ out) {
    // Bijective chunked XCD swizzle: contiguous chunks of block-space per XCD.
    const int bid = blockIdx.x;
    const int qc = NBLK / NXCD;
    const int rm = NBLK % NXCD;
    const int xcd = bid % NXCD;
    const int idx = bid / NXCD;
    const int blk = (xcd < rm ? xcd * (qc + 1)
                              : rm * (qc + 1) + (xcd - rm) * qc) + idx;

    const int c = threadIdx.x;          // 0..127 (float4 channel group)
    const f4* __restrict__ img4  = (const f4*)image;
    const f4* __restrict__ rois4 = (const f4*)rois;
    f4* __restrict__ out4 = (f4*)out;

    const int base = blk * CELLS_PER_BLK;

    Cell cl[CELLS_PER_BLK];
    #pragma unroll
    for (int i = 0; i < CELLS_PER_BLK; ++i)
        cl[i] = decode_cell(rois4, base + i);

    // Issue all 16 loads before any blend — 16 outstanding VMEM ops per thread.
    f4 v00[CELLS_PER_BLK], v01[CELLS_PER_BLK], v10[CELLS_PER_BLK], v11[CELLS_PER_BLK];
    #pragma unroll
    for (int i = 0; i < CELLS_PER_BLK; ++i) {
        v00[i] = img4[cl[i].c00 + c];
        v01[i] = img4[cl[i].c01 + c];
        v10[i] = img4[cl[i].c10 + c];
        v11[i] = img4[cl[i].c11 + c];
    }

    #pragma unroll
    for (int i = 0; i < CELLS_PER_BLK; ++i) {
        const f4 o = v00[i] * cl[i].w00 + v01[i] * cl[i].w01
                   + v10[i] * cl[i].w10 + v11[i] * cl[i].w11;
        // Output is write-once/never-read: nontemporal, spare caches for image.
        __builtin_nontemporal_store(o, &out4[(base + i) * CH4 + c]);
    }
}

extern "C" void kernel_launch(void* const* d_in, const int* in_sizes, int n_in,
                              void* d_out, int out_size, void* d_ws, size_t ws_size,
                              hipStream_t stream) {
    const float* image = (const float*)d_in[0];
    const float* rois  = (const float*)d_in[1];
    float* out = (float*)d_out;

    roi_pool_kernel<<<NBLK, CH4, 0, stream>>>(image, rois, out);
}